// Round 1
// baseline (1156.374 us; speedup 1.0000x reference)
//
#include <hip/hip_runtime.h>

// VARImputer: B=256, S=2048, F=64, ORDER=5, K=320. One batch per block/CU.
//
// Wave-specialized scan (latency restructure):
//   wave 0 (critical): lane f owns feature f. Per step: t = slot[s%5][f]
//     + W4[f]·frame[s-1] (16 uniform ds_read_b128 broadcasts + 64 fma, NO
//     shuffles), nv = m ? x : t, publish frame, store out, prefetch x/mask
//     (depth-4 register ring straight from global).
//   waves 1..4 (helpers): block W3,W2,W1,W0. Per step add W_h[f]·frame[s-1]
//     into pending slot (s+w)%5 (W0 re-initializes slot with bias+dot).
//     Slack >= 1 barrier in both directions -> single barrier/step.
//
// Sync is raw s_barrier + lgkmcnt(0) ONLY: __syncthreads would drain
// vmcnt(0) every step and expose the critical wave's HBM prefetch latency.

#define BB  256
#define SS  2048
#define FF  64
#define KK  320
#define NTH 320   // 5 waves

__device__ __forceinline__ float dot64(const float4* wr, const float4* frp)
{
    float acc[8];
#pragma unroll
    for (int j = 0; j < 8; ++j) {
        const float4 a  = frp[2 * j];
        const float4 b  = frp[2 * j + 1];
        const float4 wa = wr[2 * j];
        const float4 wb = wr[2 * j + 1];
        float s = wa.x * a.x;
        s = fmaf(wa.y, a.y, s);
        s = fmaf(wa.z, a.z, s);
        s = fmaf(wa.w, a.w, s);
        s = fmaf(wb.x, b.x, s);
        s = fmaf(wb.y, b.y, s);
        s = fmaf(wb.z, b.z, s);
        s = fmaf(wb.w, b.w, s);
        acc[j] = s;
    }
    return ((acc[0] + acc[1]) + (acc[2] + acc[3]))
         + ((acc[4] + acc[5]) + (acc[6] + acc[7]));
}

// LDS-only step barrier: publish own ds_writes, sync, pin reads after.
__device__ __forceinline__ void step_sync()
{
    asm volatile("s_waitcnt lgkmcnt(0)" ::: "memory");
    __builtin_amdgcn_s_barrier();
    __builtin_amdgcn_sched_barrier(0);
}

__global__ __launch_bounds__(NTH, 2)
void var_imputer_kernel(const float* __restrict__ x,
                        const int*   __restrict__ mask,
                        const float* __restrict__ W,
                        const float* __restrict__ bias,
                        float*       __restrict__ out)
{
    __shared__ __align__(16) float frame_buf[2 * FF];   // double-buffered frame
    __shared__ __align__(16) float slot_ring[5 * FF];   // pending ring (incl. bias)
    __shared__ __align__(16) float mean_row[FF];
    __shared__ __align__(16) float p1s[20 * FF];
    __shared__ __align__(16) float p1c[20 * FF];

    const int b   = blockIdx.x;
    const int tid = threadIdx.x;
    const int wid = tid >> 6;
    const int f   = tid & 63;

    const float* xb = x    + (size_t)b * SS * FF;
    const int*   mb = mask + (size_t)b * SS * FF;
    float*       ob = out  + (size_t)b * SS * FF;

    // wave 0 -> W4 (critical), waves 1..4 -> W3,W2,W1,W0
    const int bh = (wid == 0) ? 4 : (4 - wid);

    float4 wr[16];
    {
        const float4* wp = (const float4*)(W + (size_t)f * KK + bh * FF);
#pragma unroll
        for (int i = 0; i < 16; ++i) wr[i] = wp[i];
    }
    const float bf = bias[f];

    // ---- phase 1: per-feature mean over observed steps ----
    {
        const int f4 = tid & 15;
        const int sg = tid >> 4;          // [0,20)
        float a0 = 0.f, a1 = 0.f, a2 = 0.f, a3 = 0.f;
        float c0 = 0.f, c1 = 0.f, c2 = 0.f, c3 = 0.f;
        for (int r = sg; r < SS; r += 20) {
            const float4 xv = *(const float4*)(xb + (size_t)r * FF + 4 * f4);
            const int4   mv = *(const int4*)  (mb + (size_t)r * FF + 4 * f4);
            const float m0 = (float)mv.x, m1 = (float)mv.y;
            const float m2 = (float)mv.z, m3 = (float)mv.w;
            a0 = fmaf(xv.x, m0, a0); a1 = fmaf(xv.y, m1, a1);
            a2 = fmaf(xv.z, m2, a2); a3 = fmaf(xv.w, m3, a3);
            c0 += m0; c1 += m1; c2 += m2; c3 += m3;
        }
        const int bi = sg * FF + 4 * f4;
        p1s[bi + 0] = a0; p1s[bi + 1] = a1; p1s[bi + 2] = a2; p1s[bi + 3] = a3;
        p1c[bi + 0] = c0; p1c[bi + 1] = c1; p1c[bi + 2] = c2; p1c[bi + 3] = c3;
        __syncthreads();
        if (tid < FF) {
            float sm = 0.f, ct = 0.f;
#pragma unroll 4
            for (int g = 0; g < 20; ++g) {
                sm += p1s[g * FF + tid];
                ct += p1c[g * FF + tid];
            }
            const float mean = sm / (ct + 1e-8f);
            mean_row[tid]       = mean;
            frame_buf[FF + tid] = mean;   // frame[-1] lives in parity-1 buffer
        }
        __syncthreads();
    }

    // ---- warm-up pending slots (wave 0 only: single writer, no races) ----
    // S_h = W_h[f]·mean; slot[t] = b + sum_{h<=3-t} S_h (pad frames == mean).
    if (wid == 0) {
        float S[4];
#pragma unroll
        for (int h = 0; h < 4; ++h) {
            float4 tw[16];
            const float4* wp = (const float4*)(W + (size_t)f * KK + h * FF);
#pragma unroll
            for (int i = 0; i < 16; ++i) tw[i] = wp[i];
            S[h] = dot64(tw, (const float4*)mean_row);
        }
        slot_ring[0 * FF + f] = bf + (S[0] + S[1] + S[2] + S[3]);
        slot_ring[1 * FF + f] = bf + (S[0] + S[1] + S[2]);
        slot_ring[2 * FF + f] = bf + (S[0] + S[1]);
        slot_ring[3 * FF + f] = bf +  S[0];
        slot_ring[4 * FF + f] = bf;   // overwritten by W0-helper at step 0
    }

    // ---- critical-wave prefetch ring (depth 4) ----
    float px0 = 0.f, px1 = 0.f, px2 = 0.f, px3 = 0.f;
    int   pm0 = 0,   pm1 = 0,   pm2 = 0,   pm3 = 0;
    const float* xpf = xb + f;
    const int*   mpf = mb + f;
    float*       op  = ob + f;
    if (wid == 0) {
        px0 = xpf[0 * FF]; pm0 = mpf[0 * FF];
        px1 = xpf[1 * FF]; pm1 = mpf[1 * FF];
        px2 = xpf[2 * FF]; pm2 = mpf[2 * FF];
        px3 = xpf[3 * FF]; pm3 = mpf[3 * FF];
        __builtin_amdgcn_s_setprio(1);   // bias shared SIMD toward the chain
    }

    int coff = 0;          // critical: (s%5)*FF
    int soff = wid * FF;   // helper w: ((0+w)%5)*FF

    // ---- main scan: one barrier per step, statically-unrolled by 4 ----
#define STEP(k, PX, PM)                                                        \
    {                                                                          \
        const int s = s4 + (k);                                                \
        step_sync();  /* publishes frame[s-1] + slot writes of step s-1 */     \
        const float4* frp = (const float4*)&frame_buf[(((k) & 1) ^ 1) * FF];   \
        if (wid == 0) {                                                        \
            const float sv = slot_ring[coff + f];                              \
            const float d  = dot64(wr, frp);                                   \
            const float t  = sv + d;                                           \
            const float nv = PM ? PX : t;                                      \
            frame_buf[((k) & 1) * FF + f] = nv;                                \
            op[0] = nv; op += FF;                                              \
            int spf = s + 4; spf = (spf < SS) ? spf : (SS - 1);                \
            PX = xpf[(size_t)spf * FF];                                        \
            PM = mpf[(size_t)spf * FF];                                        \
            coff += FF; if (coff >= 5 * FF) coff = 0;                          \
        } else {                                                               \
            const float d = dot64(wr, frp);                                    \
            if (bh == 0) slot_ring[soff + f] = bf + d;                         \
            else         slot_ring[soff + f] += d;                             \
            soff += FF; if (soff >= 5 * FF) soff = 0;                          \
        }                                                                      \
    }

    for (int s4 = 0; s4 < SS; s4 += 4) {
        STEP(0, px0, pm0)
        STEP(1, px1, pm1)
        STEP(2, px2, pm2)
        STEP(3, px3, pm3)
    }
#undef STEP
}

extern "C" void kernel_launch(void* const* d_in, const int* in_sizes, int n_in,
                              void* d_out, int out_size, void* d_ws, size_t ws_size,
                              hipStream_t stream)
{
    const float* x    = (const float*)d_in[0];
    const int*   mask = (const int*)d_in[1];
    const float* W    = (const float*)d_in[2];
    const float* bias = (const float*)d_in[3];
    float*       out  = (float*)d_out;

    var_imputer_kernel<<<dim3(BB), dim3(NTH), 0, stream>>>(x, mask, W, bias, out);
}

// Round 2
// 1099.400 us; speedup vs baseline: 1.0518x; 1.0518x over previous
//
#include <hip/hip_runtime.h>

// VARImputer: B=256, S=2048, F=64, ORDER=5, K=320. One batch per block/CU.
//
// R=4 pending-accumulator scan, 4 waves (256 thr), lgkm-only barrier:
//   lane (wq, z, fo): f = 16*wq + fo owns output feature f; z in [0,4) owns
//   K-subslice [16z,16z+16) of each of the 5 W lag-blocks (wr[20] float4).
//   Per step: read frame[s-1] slice ONCE (4 x b128, 2-way bank alias = free),
//   critical dot = p1 + Wb4.slice (16 fma) -> xor16+xor32 butterfly -> select
//   -> z==0 publishes frame[s].
//   Pending r-chain (lag 2..5, 64 fma) is retimed to use the PREVIOUS frame
//   slice (registers) so it issues inside the ds_read latency window:
//     p1 = r1 + Wb3.fprev ; r1' = r2 + Wb2.fprev ; r2' = r3 + Wb1.fprev ;
//     r3' = Wb0.fprev
//   All global traffic is chunked (32 steps): x/mask sentinel-fused into one
//   LDS float (missing -> 1e30f), outputs accumulated in win rows, stored as
//   coalesced float4 once per chunk. Per-step sync = s_barrier + lgkmcnt(0)
//   only (no vmcnt drain -> chunk prefetch loads stay in flight).

#define BB  256
#define SS  2048
#define FF  64
#define KK  320
#define CH  32
#define NCH (SS / CH)   // 64
#define NTH 256         // 4 waves
#define BIGV 1e30f
#define THRV 1e29f

__device__ __forceinline__ float dot16(const float4* __restrict__ w,
                                       const float4* __restrict__ v)
{
    float s0 = w[0].x * v[0].x;
    s0 = fmaf(w[0].y, v[0].y, s0);
    s0 = fmaf(w[0].z, v[0].z, s0);
    s0 = fmaf(w[0].w, v[0].w, s0);
    float s1 = w[1].x * v[1].x;
    s1 = fmaf(w[1].y, v[1].y, s1);
    s1 = fmaf(w[1].z, v[1].z, s1);
    s1 = fmaf(w[1].w, v[1].w, s1);
    float s2 = w[2].x * v[2].x;
    s2 = fmaf(w[2].y, v[2].y, s2);
    s2 = fmaf(w[2].z, v[2].z, s2);
    s2 = fmaf(w[2].w, v[2].w, s2);
    float s3 = w[3].x * v[3].x;
    s3 = fmaf(w[3].y, v[3].y, s3);
    s3 = fmaf(w[3].z, v[3].z, s3);
    s3 = fmaf(w[3].w, v[3].w, s3);
    return (s0 + s1) + (s2 + s3);
}

// LDS-only step barrier: publish own ds ops, sync, pin reads after.
__device__ __forceinline__ void step_sync()
{
    asm volatile("s_waitcnt lgkmcnt(0)" ::: "memory");
    __builtin_amdgcn_s_barrier();
    __builtin_amdgcn_sched_barrier(0);
}

__global__ __launch_bounds__(NTH, 1)
void var_imputer_kernel(const float* __restrict__ x,
                        const int*   __restrict__ mask,
                        const float* __restrict__ W,
                        const float* __restrict__ bias,
                        float*       __restrict__ out)
{
    __shared__ __align__(16) float win[(1 + CH) * FF];  // row0 = frame[s-1] seed
    __shared__ __align__(16) float cxe[CH * FF];        // observed x or BIGV
    __shared__ __align__(16) float p1s[16 * FF];
    __shared__ __align__(16) float p1c[16 * FF];

    const int b   = blockIdx.x;
    const int tid = threadIdx.x;
    const int wq  = tid >> 6;
    const int ln  = tid & 63;
    const int z   = ln >> 4;
    const int fo  = ln & 15;
    const int f   = wq * 16 + fo;

    const float* xb = x    + (size_t)b * SS * FF;
    const int*   mb = mask + (size_t)b * SS * FF;
    float*       ob = out  + (size_t)b * SS * FF;

    // ---- W into registers: wr[bk*4+j] covers W[f][bk*64 + 16z .. +16) ----
    float4 wr[20];
#pragma unroll
    for (int bk = 0; bk < 5; ++bk) {
        const float4* wp = (const float4*)(W + (size_t)f * KK + bk * 64 + 16 * z);
        wr[bk * 4 + 0] = wp[0];
        wr[bk * 4 + 1] = wp[1];
        wr[bk * 4 + 2] = wp[2];
        wr[bk * 4 + 3] = wp[3];
    }
    const float breg = bias[f];

    // ---- phase 1: per-feature mean over observed steps ----
    {
        const int f4 = tid & 15;
        const int sg = tid >> 4;          // [0,16)
        float a0 = 0.f, a1 = 0.f, a2 = 0.f, a3 = 0.f;
        float c0 = 0.f, c1 = 0.f, c2 = 0.f, c3 = 0.f;
        const float* xp = xb + (size_t)sg * FF + f4 * 4;
        const int*   mp = mb + (size_t)sg * FF + f4 * 4;
        for (int k = 0; k < SS / 16; ++k) {
            const float4 xv = *(const float4*)(xp + (size_t)k * 16 * FF);
            const int4   mv = *(const int4*)  (mp + (size_t)k * 16 * FF);
            const float m0 = (float)mv.x, m1 = (float)mv.y;
            const float m2 = (float)mv.z, m3 = (float)mv.w;
            a0 = fmaf(xv.x, m0, a0); a1 = fmaf(xv.y, m1, a1);
            a2 = fmaf(xv.z, m2, a2); a3 = fmaf(xv.w, m3, a3);
            c0 += m0; c1 += m1; c2 += m2; c3 += m3;
        }
        const int bi = sg * FF + f4 * 4;
        p1s[bi + 0] = a0; p1s[bi + 1] = a1; p1s[bi + 2] = a2; p1s[bi + 3] = a3;
        p1c[bi + 0] = c0; p1c[bi + 1] = c1; p1c[bi + 2] = c2; p1c[bi + 3] = c3;
        __syncthreads();
        if (tid < FF) {
            float sm = 0.f, ct = 0.f;
#pragma unroll 4
            for (int g = 0; g < 16; ++g) {
                sm += p1s[g * FF + tid];
                ct += p1c[g * FF + tid];
            }
            win[tid] = sm / (ct + 1e-8f);   // row 0 = frame[-1] = mean
        }
    }
    __syncthreads();

    // ---- chunk 0 load + stage, chunk 1 prefetch ----
    float4 crx[2]; int4 crm[2];
    crx[0] = ((const float4*)xb)[tid * 2 + 0];
    crx[1] = ((const float4*)xb)[tid * 2 + 1];
    crm[0] = ((const int4*)mb)[tid * 2 + 0];
    crm[1] = ((const int4*)mb)[tid * 2 + 1];
    {
        float4 s0, s1;
        s0.x = crm[0].x ? crx[0].x : BIGV;
        s0.y = crm[0].y ? crx[0].y : BIGV;
        s0.z = crm[0].z ? crx[0].z : BIGV;
        s0.w = crm[0].w ? crx[0].w : BIGV;
        s1.x = crm[1].x ? crx[1].x : BIGV;
        s1.y = crm[1].y ? crx[1].y : BIGV;
        s1.z = crm[1].z ? crx[1].z : BIGV;
        s1.w = crm[1].w ? crx[1].w : BIGV;
        ((float4*)cxe)[tid * 2 + 0] = s0;
        ((float4*)cxe)[tid * 2 + 1] = s1;
    }
    crx[0] = ((const float4*)(xb + (size_t)CH * FF))[tid * 2 + 0];
    crx[1] = ((const float4*)(xb + (size_t)CH * FF))[tid * 2 + 1];
    crm[0] = ((const int4*)(mb + (size_t)CH * FF))[tid * 2 + 0];
    crm[1] = ((const int4*)(mb + (size_t)CH * FF))[tid * 2 + 1];

    // ---- warm-up pendings from mean frames (per-lane partials) ----
    const float4* fb4 = ((const float4*)win) + 4 * z;
    float4 fO0, fO1, fO2, fO3, fN0, fN1, fN2, fN3;
    fO0 = fb4[0]; fO1 = fb4[1]; fO2 = fb4[2]; fO3 = fb4[3];
    float r1, r2, r3;
    {
        float4 fm[4] = {fO0, fO1, fO2, fO3};
        const float S0 = dot16(&wr[0],  fm);
        const float S1 = dot16(&wr[4],  fm);
        const float S2 = dot16(&wr[8],  fm);
        r1 = S0 + S1 + S2;
        r2 = S0 + S1;
        r3 = S0;
    }
    __syncthreads();   // cxe chunk 0 + row 0 visible everywhere

    // ---- main scan: one lgkm-barrier per step ----
#define STEP(S, FA0, FA1, FA2, FA3, FB0, FB1, FB2, FB3)                        \
    {                                                                          \
        step_sync();                                                           \
        FB0 = fb4[(S) * 16 + 0];                                               \
        FB1 = fb4[(S) * 16 + 1];                                               \
        FB2 = fb4[(S) * 16 + 2];                                               \
        FB3 = fb4[(S) * 16 + 3];                                               \
        const float cv = cxe[(S) * FF + f];                                    \
        float4 fo_[4] = {FA0, FA1, FA2, FA3};                                  \
        const float p1 = r1 + dot16(&wr[12], fo_);                             \
        r1 = r2 + dot16(&wr[8], fo_);                                          \
        r2 = r3 + dot16(&wr[4], fo_);                                          \
        r3 =      dot16(&wr[0], fo_);                                          \
        float4 fn_[4] = {FB0, FB1, FB2, FB3};                                  \
        float t = p1 + dot16(&wr[16], fn_);                                    \
        t += __shfl_xor(t, 16);                                                \
        t += __shfl_xor(t, 32);                                                \
        const float nv = (cv < THRV) ? cv : (t + breg);                        \
        if (ln < 16) win[((S) + 1) * FF + f] = nv;                             \
    }
#define STEP2(S)                                                               \
    STEP(S,     fO0, fO1, fO2, fO3, fN0, fN1, fN2, fN3)                        \
    STEP((S)+1, fN0, fN1, fN2, fN3, fO0, fO1, fO2, fO3)

    for (int c = 0; c < NCH; ++c) {
        STEP2(0)  STEP2(2)  STEP2(4)  STEP2(6)
        STEP2(8)  STEP2(10) STEP2(12) STEP2(14)
        STEP2(16) STEP2(18) STEP2(20) STEP2(22)
        STEP2(24) STEP2(26) STEP2(28) STEP2(30)

        // ---- chunk boundary ----
        step_sync();   // row CH + all step writes visible; cxe reads done

        // store rows 1..CH (this chunk's outputs), coalesced
        {
            const float4 o0 = ((const float4*)&win[FF])[tid * 2 + 0];
            const float4 o1 = ((const float4*)&win[FF])[tid * 2 + 1];
            float4* od = (float4*)(ob + (size_t)c * CH * FF);
            od[tid * 2 + 0] = o0;
            od[tid * 2 + 1] = o1;
        }
        // rebase: row CH -> row 0 (next chunk's frame[s-1])
        if (tid < FF) win[tid] = win[CH * FF + tid];

        if (c + 1 < NCH) {
            // stage chunk c+1 from prefetched regs (compiler waits vmcnt)
            float4 s0, s1;
            s0.x = crm[0].x ? crx[0].x : BIGV;
            s0.y = crm[0].y ? crx[0].y : BIGV;
            s0.z = crm[0].z ? crx[0].z : BIGV;
            s0.w = crm[0].w ? crx[0].w : BIGV;
            s1.x = crm[1].x ? crx[1].x : BIGV;
            s1.y = crm[1].y ? crx[1].y : BIGV;
            s1.z = crm[1].z ? crx[1].z : BIGV;
            s1.w = crm[1].w ? crx[1].w : BIGV;
            ((float4*)cxe)[tid * 2 + 0] = s0;
            ((float4*)cxe)[tid * 2 + 1] = s1;
            if (c + 2 < NCH) {
                const float* xn = xb + (size_t)(c + 2) * CH * FF;
                const int*   mn = mb + (size_t)(c + 2) * CH * FF;
                crx[0] = ((const float4*)xn)[tid * 2 + 0];
                crx[1] = ((const float4*)xn)[tid * 2 + 1];
                crm[0] = ((const int4*)mn)[tid * 2 + 0];
                crm[1] = ((const int4*)mn)[tid * 2 + 1];
            }
        }
        step_sync();   // staging + rebase visible before next chunk
    }
#undef STEP2
#undef STEP
}

extern "C" void kernel_launch(void* const* d_in, const int* in_sizes, int n_in,
                              void* d_out, int out_size, void* d_ws, size_t ws_size,
                              hipStream_t stream)
{
    const float* x    = (const float*)d_in[0];
    const int*   mask = (const int*)d_in[1];
    const float* W    = (const float*)d_in[2];
    const float* bias = (const float*)d_in[3];
    float*       out  = (float*)d_out;

    var_imputer_kernel<<<dim3(BB), dim3(NTH), 0, stream>>>(x, mask, W, bias, out);
}